// Round 2
// baseline (465.489 us; speedup 1.0000x reference)
//
#include <hip/hip_runtime.h>

// FunctionCorrelationTranspose:
// out[b,c,h,w] = (1/C) * sum_{P=0..8,O=0..8} input[b, P*9+O, h, w] * second[b, c, h+P-4, w+O-4]
// B=8, C=256, H=W=128, zero padding outside image.
//
// R1 changes vs baseline (280 us dispatch):
//  - ping-pong register prefetch of next-P weights (was: 72 exposed VMEM stalls/thread)
//  - staging via global_load_lds width-16 (was: 18 load + 18 ds_write per chunk)
//  - nontemporal out stores (keep weight tile L3-resident across the 8x chunk re-reads)
// R2: fix nontemporal store type (native ext_vector_type, not HIP float4 class)

#define MD 4

constexpr int Bc = 8, Cc = 256, Hc = 128, Wc = 128;
constexpr int HW = Hc * Wc;
constexpr int TH = 16, TW = 16;          // spatial tile per block
constexpr int NSLOT = 8;                 // channel slots (threads along C)
constexpr int NC = 4;                    // channels per thread per chunk
constexpr int CHUNK = NSLOT * NC;        // 32 channels staged in LDS at a time
constexpr int NCHUNK = Cc / CHUNK;       // 8
constexpr int SROWS = TH + 2 * MD;       // 24
constexpr int SCOLS = TW + 2 * MD;       // 24
constexpr int CH_STRIDE = SROWS * SCOLS + 4; // 580 floats; slots hit bank-starts {0,4,..,28}
constexpr int SLOTS_PER_CH = CH_STRIDE / 4;  // 145 16B-slots per channel (144 data + 1 pad)
constexpr int TOT_SLOTS = CHUNK * SLOTS_PER_CH; // 4640
constexpr int NPIX = 8;                  // pixels per thread (contiguous in w)

typedef float f32x4 __attribute__((ext_vector_type(4)));

// load the 9 taps of weight-row PP for this thread's 8 pixels into dst[18] (float4 pairs)
#define LOADW(dst, PP)                                                  \
    {                                                                   \
        _Pragma("unroll")                                               \
        for (int o = 0; o < 9; ++o) {                                   \
            const float* wp = wbase + (size_t)((PP) * 9 + o) * HW;      \
            dst[2 * o]     = *reinterpret_cast<const float4*>(wp);      \
            dst[2 * o + 1] = *reinterpret_cast<const float4*>(wp + 4);  \
        }                                                               \
    }

// accumulate one weight-row PP using weights in wcur[18]
#define COMPUTE(wcur, PP)                                                        \
    {                                                                            \
        _Pragma("unroll")                                                        \
        for (int j = 0; j < NC; ++j) {                                           \
            const int cl = j * NSLOT + slot;                                     \
            const float* srow = &sS[cl * CH_STRIDE + (r + (PP)) * SCOLS + seg * NPIX]; \
            float s[16];                                                         \
            _Pragma("unroll")                                                    \
            for (int t = 0; t < 4; ++t) {                                        \
                float4 v = *reinterpret_cast<const float4*>(srow + 4 * t);       \
                s[4*t] = v.x; s[4*t+1] = v.y; s[4*t+2] = v.z; s[4*t+3] = v.w;    \
            }                                                                    \
            _Pragma("unroll")                                                    \
            for (int o = 0; o < 9; ++o) {                                        \
                acc[j][0] = fmaf(wcur[2*o].x,   s[o + 0], acc[j][0]);            \
                acc[j][1] = fmaf(wcur[2*o].y,   s[o + 1], acc[j][1]);            \
                acc[j][2] = fmaf(wcur[2*o].z,   s[o + 2], acc[j][2]);            \
                acc[j][3] = fmaf(wcur[2*o].w,   s[o + 3], acc[j][3]);            \
                acc[j][4] = fmaf(wcur[2*o+1].x, s[o + 4], acc[j][4]);            \
                acc[j][5] = fmaf(wcur[2*o+1].y, s[o + 5], acc[j][5]);            \
                acc[j][6] = fmaf(wcur[2*o+1].z, s[o + 6], acc[j][6]);            \
                acc[j][7] = fmaf(wcur[2*o+1].w, s[o + 7], acc[j][7]);            \
            }                                                                    \
        }                                                                        \
    }

__global__ __launch_bounds__(256, 2)
void fct_kernel(const float* __restrict__ inp,    // (B, 81, H, W)
                const float* __restrict__ second, // (B, C, H, W)
                float* __restrict__ out)          // (B, C, H, W)
{
    __shared__ float sS[CHUNK * CH_STRIDE]; // 74,240 B -> 2 blocks/CU

    const int tid   = threadIdx.x;
    const int slot  = tid & (NSLOT - 1);   // 0..7
    const int group = tid >> 3;            // 0..31
    const int r     = group >> 1;          // 0..15 tile row
    const int seg   = group & 1;           // 0..1  8-px segment in row
    const int wid   = tid >> 6;            // wave id 0..3

    const int bx   = blockIdx.x;           // 0..511
    const int b    = bx >> 6;
    const int tile = bx & 63;
    const int th0  = (tile >> 3) * TH;
    const int tw0  = (tile & 7) * TW;

    const int h   = th0 + r;
    const int wc0 = tw0 + seg * NPIX;

    // zero LDS once: OOB halo cells must read as 0.  The staging below never
    // writes OOB slots (exec-masked) nor the per-channel pad slot, so zeros persist.
    {
        float4 z = make_float4(0.f, 0.f, 0.f, 0.f);
        float4* s4 = reinterpret_cast<float4*>(sS);
        for (int i = tid; i < TOT_SLOTS; i += 256) s4[i] = z;
    }

    const float* wbase = inp + (size_t)b * 81 * HW + (size_t)h * Wc + wc0;
    const float scale = 1.0f / (float)Cc;

    for (int chunk = 0; chunk < NCHUNK; ++chunk) {
        __syncthreads(); // previous chunk's compute done before overwrite (and after zeroing)

        float4 wA[18], wB[18];

        // prime P=0 weights: latency hidden under the staging drain below
        LOADW(wA, 0);

        // ---- stage second[b, chunk*32 .. +32) halo tile into LDS, async ----
        // LDS image is linear in 16B slots: slot m = ch*145 + k, k<144 data, k==144 pad.
        // global_load_lds writes wave-uniform base + lane*16, which matches m exactly.
        {
            const int c0 = chunk * CHUNK;
            #pragma unroll
            for (int it = 0; it < 19; ++it) {
                const int m = it * 256 + tid;
                if (m < TOT_SLOTS) {
                    const int ch   = m / SLOTS_PER_CH;      // /145 (magic mul)
                    const int k    = m - ch * SLOTS_PER_CH; // 0..144
                    const int row  = k / 6;
                    const int x    = k - row * 6;
                    const int grow = th0 - MD + row;
                    const int gcol = tw0 - MD + 4 * x;      // multiple of 4: fully in or out
                    float* ldsb = &sS[(it * 256 + wid * 64) * 4]; // wave-uniform
                    if (k < 144 && grow >= 0 && grow < Hc && gcol >= 0 && gcol <= Wc - 4) {
                        const float* gp = second +
                            (((size_t)(b * Cc + c0 + ch)) * Hc + grow) * Wc + gcol;
                        __builtin_amdgcn_global_load_lds(
                            (const __attribute__((address_space(1))) void*)gp,
                            (__attribute__((address_space(3))) void*)ldsb,
                            16, 0, 0);
                    }
                }
            }
        }
        __syncthreads(); // drains vmcnt: staging AND primed wA both complete

        float acc[NC][NPIX];
        #pragma unroll
        for (int j = 0; j < NC; ++j)
            #pragma unroll
            for (int i = 0; i < NPIX; ++i) acc[j][i] = 0.f;

        // software-pipelined P loop: prefetch next row's weights into the other
        // buffer, then compute ~288 FMAs on the current one (covers VMEM latency).
        #pragma unroll 1
        for (int Ph = 0; Ph < 9; Ph += 2) {
            if (Ph + 1 < 9) LOADW(wB, Ph + 1);
            COMPUTE(wA, Ph);
            if (Ph + 1 < 9) {
                if (Ph + 2 < 9) LOADW(wA, Ph + 2);
                COMPUTE(wB, Ph + 1);
            }
        }

        // ---- store this chunk's outputs (write-once stream: nontemporal) ----
        #pragma unroll
        for (int j = 0; j < NC; ++j) {
            const int c = chunk * CHUNK + j * NSLOT + slot;
            float* op = out + (((size_t)(b * Cc + c)) * Hc + h) * Wc + wc0;
            f32x4 v0 = { acc[j][0] * scale, acc[j][1] * scale,
                         acc[j][2] * scale, acc[j][3] * scale };
            f32x4 v1 = { acc[j][4] * scale, acc[j][5] * scale,
                         acc[j][6] * scale, acc[j][7] * scale };
            __builtin_nontemporal_store(v0, reinterpret_cast<f32x4*>(op));
            __builtin_nontemporal_store(v1, reinterpret_cast<f32x4*>(op + 4));
        }
    }
}

extern "C" void kernel_launch(void* const* d_in, const int* in_sizes, int n_in,
                              void* d_out, int out_size, void* d_ws, size_t ws_size,
                              hipStream_t stream) {
    const float* inp    = (const float*)d_in[0]; // (8, 81, 128, 128)
    const float* second = (const float*)d_in[1]; // (8, 256, 128, 128)
    float* outp         = (float*)d_out;         // (8, 256, 128, 128)

    dim3 grid(Bc * (Hc / TH) * (Wc / TW)); // 512 blocks
    dim3 block(256);
    fct_kernel<<<grid, block, 0, stream>>>(inp, second, outp);
}